// Round 10
// baseline (213.578 us; speedup 1.0000x reference)
//
#include <hip/hip_runtime.h>
#include <stdint.h>

// MultiHeadSelfAttention: E=1024, H=16, S=4096, half=512, Dh=32, scale=sqrt(64)=8
// Inputs fp32. bf16 convert -> double-buffered 128-tile MFMA GEMMs -> split-K
// flash attention v3: waves partition KEYS (16 each, all 64 q); softmaxed S in
// C/D layout IS the K=16 PV a-operand -> P never touches LDS. K direct from
// global; only V^T staged in LDS. Fixed-max softmax, exact additive sp-merge.

#define SEQ    4096
#define DMODEL 1024
#define DHALF  512
#define NH     16
#define DH     32
#define NSPLIT 2
#define KSPAN  (SEQ / NSPLIT)

typedef __attribute__((ext_vector_type(4))) float facc4;
typedef __attribute__((ext_vector_type(8))) short bfrag8;
typedef __attribute__((ext_vector_type(4))) short bpack4;

#define MFMA_BF16(a, b, c)  __builtin_amdgcn_mfma_f32_16x16x32_bf16((a), (b), (c), 0, 0, 0)
#define MFMA_BF16_K16(a, b, c) __builtin_amdgcn_mfma_f32_16x16x16bf16_1k((a), (b), (c), 0, 0, 0)

static __device__ __forceinline__ uint16_t f2b(float x) {
    uint32_t u = __float_as_uint(x);
    return (uint16_t)((u + 0x7FFFu + ((u >> 16) & 1u)) >> 16);  // RNE
}
static __device__ __forceinline__ float b2f(uint16_t b) {
    return __uint_as_float(((uint32_t)b) << 16);
}

static __device__ __forceinline__ bfrag8 cvt8(const float* __restrict__ s) {
    float4 a = *(const float4*)s;
    float4 b = *(const float4*)(s + 4);
    bfrag8 r;
    r[0] = (short)f2b(a.x); r[1] = (short)f2b(a.y);
    r[2] = (short)f2b(a.z); r[3] = (short)f2b(a.w);
    r[4] = (short)f2b(b.x); r[5] = (short)f2b(b.y);
    r[6] = (short)f2b(b.z); r[7] = (short)f2b(b.w);
    return r;
}

// One fused conversion kernel: blocks [0,1024) do x-left, [1024,1664) weights.
__global__ __launch_bounds__(256) void convert_all(
    const float* __restrict__ x,  const float* __restrict__ Wq,
    const float* __restrict__ Wk, const float* __restrict__ Wv,
    const float* __restrict__ Wo,
    uint16_t* __restrict__ xbf, uint16_t* __restrict__ Wqb,
    uint16_t* __restrict__ Wkb, uint16_t* __restrict__ Wvb,
    uint16_t* __restrict__ Wob)
{
    int bid = blockIdx.x;
    if (bid < 1024) {
        int t   = bid * 256 + threadIdx.x;
        int row = t >> 6;
        int cb  = (t & 63) << 3;
        *(bfrag8*)&xbf[(size_t)row * DHALF + cb] = cvt8(&x[(size_t)row * DMODEL + cb]);
    } else {
        int zz = bid - 1024;
        const float* src; uint16_t* dst; size_t off;
        if      (zz < 128) { src = Wq; dst = Wqb; off = (size_t)zz * 2048; }
        else if (zz < 256) { src = Wk; dst = Wkb; off = (size_t)(zz - 128) * 2048; }
        else if (zz < 384) { src = Wv; dst = Wvb; off = (size_t)(zz - 256) * 2048; }
        else               { src = Wo; dst = Wob; off = (size_t)(zz - 384) * 2048; }
        size_t i = off + (size_t)threadIdx.x * 8;
        *(bfrag8*)&dst[i] = cvt8(&src[i]);
    }
}

// ---------------------------------------------------------------------------
// 128x128-tile bf16 GEMM, double-buffered LDS (unchanged from R9).
// ---------------------------------------------------------------------------
__device__ __forceinline__ void gemm128(
    const uint16_t* __restrict__ A, int lda,
    const uint16_t* __restrict__ B, int ldb,
    void* __restrict__ C, int ldc, int cF32,
    const float* __restrict__ bias, float scale,
    int Kd, int m0, int n0)
{
    __shared__ __align__(16) uint16_t As[2][128 * 40];
    __shared__ __align__(16) uint16_t Bs[2][128 * 40];

    const int tid  = threadIdx.x;
    const int lane = tid & 63;
    const int wv   = tid >> 6;
    const int lo   = lane & 15;
    const int quad = lane >> 4;
    const int srow = tid >> 2;
    const int skq  = (tid & 3) * 8;
    const int rb   = (wv >> 1) * 64;
    const int cb   = (wv & 1) * 64;

    const facc4 ZACC = {0.f, 0.f, 0.f, 0.f};
    facc4 acc[4][4];
#pragma unroll
    for (int i = 0; i < 4; ++i)
#pragma unroll
        for (int j = 0; j < 4; ++j) acc[i][j] = ZACC;

    const uint16_t* pA0 = &A[(size_t)(m0 + srow) * lda + skq];
    const uint16_t* pA1 = &A[(size_t)(m0 + srow + 64) * lda + skq];
    const uint16_t* pB0 = &B[(size_t)(n0 + srow) * ldb + skq];
    const uint16_t* pB1 = &B[(size_t)(n0 + srow + 64) * ldb + skq];

    bfrag8 ra0 = *(const bfrag8*)pA0;
    bfrag8 ra1 = *(const bfrag8*)pA1;
    bfrag8 rb0 = *(const bfrag8*)pB0;
    bfrag8 rb1 = *(const bfrag8*)pB1;

    *(bfrag8*)&As[0][srow * 40 + skq]        = ra0;
    *(bfrag8*)&As[0][(srow + 64) * 40 + skq] = ra1;
    *(bfrag8*)&Bs[0][srow * 40 + skq]        = rb0;
    *(bfrag8*)&Bs[0][(srow + 64) * 40 + skq] = rb1;
    __syncthreads();

    int p = 0;
    for (int kt = 0; kt < Kd; kt += 32) {
        const bool more = (kt + 32 < Kd);
        if (more) {
            ra0 = *(const bfrag8*)(pA0 + kt + 32);
            ra1 = *(const bfrag8*)(pA1 + kt + 32);
            rb0 = *(const bfrag8*)(pB0 + kt + 32);
            rb1 = *(const bfrag8*)(pB1 + kt + 32);
        }

        bfrag8 af[4], bf[4];
#pragma unroll
        for (int i = 0; i < 4; ++i) {
            af[i] = *(const bfrag8*)&As[p][(rb + i * 16 + lo) * 40 + quad * 8];
            bf[i] = *(const bfrag8*)&Bs[p][(cb + i * 16 + lo) * 40 + quad * 8];
        }
#pragma unroll
        for (int i = 0; i < 4; ++i)
#pragma unroll
            for (int j = 0; j < 4; ++j)
                acc[i][j] = MFMA_BF16(af[i], bf[j], acc[i][j]);

        if (more) {
            *(bfrag8*)&As[1 - p][srow * 40 + skq]        = ra0;
            *(bfrag8*)&As[1 - p][(srow + 64) * 40 + skq] = ra1;
            *(bfrag8*)&Bs[1 - p][srow * 40 + skq]        = rb0;
            *(bfrag8*)&Bs[1 - p][(srow + 64) * 40 + skq] = rb1;
            __syncthreads();
            p ^= 1;
        }
    }

#pragma unroll
    for (int j = 0; j < 4; ++j) {
        int col  = n0 + cb + j * 16 + lo;
        float bv = bias ? bias[col] : 0.f;
#pragma unroll
        for (int i = 0; i < 4; ++i) {
#pragma unroll
            for (int r = 0; r < 4; ++r) {
                int row = m0 + rb + i * 16 + quad * 4 + r;
                float v = acc[i][j][r] * scale + bv;
                if (cF32) ((float*)C)[(size_t)row * ldc + col] = v;
                else      ((uint16_t*)C)[(size_t)row * ldc + col] = f2b(v);
            }
        }
    }
}

#define SC_Q (0.125f * 1.4426950408889634f)  // softmax scale * log2(e), folded into Q

__global__ __launch_bounds__(256, 2) void qkv_kernel(
    const uint16_t* __restrict__ xbf,
    const uint16_t* __restrict__ Wqb, const uint16_t* __restrict__ Wkb,
    const uint16_t* __restrict__ Wvb,
    uint16_t* __restrict__ Q, uint16_t* __restrict__ K, uint16_t* __restrict__ V)
{
    const int z = blockIdx.z;
    const uint16_t* W = (z == 0) ? Wqb : (z == 1) ? Wkb : Wvb;
    uint16_t* Out     = (z == 0) ? Q   : (z == 1) ? K   : V;
    float scale       = (z == 0) ? SC_Q : 1.0f;
    gemm128(xbf, DHALF, W, DHALF, Out, DHALF, 0, nullptr, scale, DHALF,
            blockIdx.y * 128, blockIdx.x * 128);
}

__global__ __launch_bounds__(256, 2) void outproj_kernel(
    const uint16_t* __restrict__ O, const uint16_t* __restrict__ Wob,
    const float* __restrict__ bo, float* __restrict__ Y)
{
    gemm128(O, DHALF, Wob, DHALF, Y, DMODEL, 1, bo, 1.0f, DHALF,
            blockIdx.y * 128, blockIdx.x * 128);
}

// ---------------------------------------------------------------------------
// Flash attention v3: block = (64 q, head, sp-split); wave wv owns keys
// [wv*16, wv*16+16) of each 64-key tile, covering ALL 64 q.
//   S: mfma_16x16x32(kf, qf[t]) -> sacc[t] = S[key=wv16+quad*4+r][q=t*16+lo]
//   softmaxed sacc packed per-lane = EXACTLY the K=16 a-operand
//   PV: mfma_16x16x16(pfrag[t], vfrag[dt]) -> O[q=t16+quad*4+r][d=dt*16+lo]
// K fragments direct from global (no LDS, no reuse loss: 1 wave per subtile).
// V^T staged in LDS (swizzled), 8B read per dt. End: cross-wave fp32 O/l
// reduction in LDS, then unnormalized bf16 Op + l per sp (combine as before).
// ---------------------------------------------------------------------------
__global__ __launch_bounds__(256) void attn_kernel(
    const uint16_t* __restrict__ Q, const uint16_t* __restrict__ Kb,
    const uint16_t* __restrict__ Vb, uint16_t* __restrict__ Op,
    float* __restrict__ lbuf)
{
    __shared__ __align__(16) uint16_t Vt[2][32 * 64];  // V^T [d][key], swizzled
    __shared__ float Ored[64][33];                     // cross-wave O reduction
    __shared__ float lsh[4][64];                       // per-wave l per q

    const int tid  = threadIdx.x;
    const int lane = tid & 63;
    const int wv   = tid >> 6;
    const int lo   = lane & 15;
    const int quad = lane >> 4;
    const int h    = blockIdx.y;
    const int q0   = blockIdx.x * 64;
    const int sp   = blockIdx.z;
    const int srow = tid >> 2;       // staging key row 0..63
    const int skq  = (tid & 3) * 8;  // staging d offset

    const facc4 ZACC = {0.f, 0.f, 0.f, 0.f};

    // Q fragments (loop-invariant, b-operand): B[n=lo][k=quad*8+j]
    bfrag8 qf[4];
#pragma unroll
    for (int t = 0; t < 4; ++t)
        qf[t] = *(const bfrag8*)&Q[(size_t)(q0 + t * 16 + lo) * DHALF + h * DH + quad * 8];

    // Vt write offsets (16B-block rotation swizzle, as R8)
    int vt_w[8];
#pragma unroll
    for (int j = 0; j < 8; ++j) {
        int d  = skq + j;
        int Rd = ((d & 7) + 2 * (d >> 3)) & 7;
        vt_w[j] = d * 64 + ((((srow >> 3) + Rd) & 7) << 3) + (srow & 7);
    }
    // Vt read offsets: V^T[d=dt*16+lo][key = wv*16 + quad*4 + j], j=0..3 (b64)
    int vt_r[2];
#pragma unroll
    for (int dt = 0; dt < 2; ++dt) {
        int d  = dt * 16 + lo;
        int Rd = ((d & 7) + 2 * (d >> 3)) & 7;
        vt_r[dt] = d * 64 + ((((2 * wv + (quad >> 1)) + Rd) & 7) << 3) + (quad & 1) * 4;
    }

    // K fragment global base: A[m=lo -> key=wv*16+lo][k=quad*8+j -> d]
    const uint16_t* pK = &Kb[(size_t)(wv * 16 + lo) * DHALF + h * DH + quad * 8];
    const uint16_t* pV = &Vb[(size_t)srow * DHALF + h * DH + skq];

    facc4 oacc[4][2];
#pragma unroll
    for (int t = 0; t < 4; ++t) { oacc[t][0] = ZACC; oacc[t][1] = ZACC; }
    float lp[4] = {0.f, 0.f, 0.f, 0.f};

    const int kb0  = sp * KSPAN;
    const int kend = kb0 + KSPAN;

    bfrag8 kf   = *(const bfrag8*)(pK + (size_t)kb0 * DHALF);
    float4 vreg = *(const float4*)(pV + (size_t)kb0 * DHALF);

    // prologue: stage Vt[0]
    {
        const uint16_t* vp = (const uint16_t*)&vreg;
#pragma unroll
        for (int j = 0; j < 8; ++j) Vt[0][vt_w[j]] = vp[j];
    }
    __syncthreads();

    int p = 0;
    for (int kb = kb0; kb < kend; kb += 64) {
        const bool more = (kb + 64 < kend);
        bfrag8 kf2;
        if (more) {  // fire-and-forget prefetch
            kf2  = *(const bfrag8*)(pK + (size_t)(kb + 64) * DHALF);
            vreg = *(const float4*)(pV + (size_t)(kb + 64) * DHALF);
        }

        bpack4 vf[2];
        vf[0] = *(const bpack4*)&Vt[p][vt_r[0]];
        vf[1] = *(const bpack4*)&Vt[p][vt_r[1]];

#pragma unroll
        for (int t = 0; t < 4; ++t) {
            facc4 s = MFMA_BF16(kf, qf[t], ZACC);  // S[key=wv16+q4+r][q=t16+lo]
            float p0 = __builtin_amdgcn_exp2f(s[0]);
            float p1 = __builtin_amdgcn_exp2f(s[1]);
            float p2 = __builtin_amdgcn_exp2f(s[2]);
            float p3 = __builtin_amdgcn_exp2f(s[3]);
            lp[t] += (p0 + p1) + (p2 + p3);
            uint32_t u0 = __float_as_uint(p0) + 0x8000u;
            uint32_t u1 = __float_as_uint(p1) + 0x8000u;
            uint32_t u2 = __float_as_uint(p2) + 0x8000u;
            uint32_t u3 = __float_as_uint(p3) + 0x8000u;
            uint2 w;
            w.x = __builtin_amdgcn_perm(u1, u0, 0x07060302u);
            w.y = __builtin_amdgcn_perm(u3, u2, 0x07060302u);
            bpack4 pf = *(bpack4*)&w;              // a-operand K=16: A[q][key]
#pragma unroll
            for (int dt = 0; dt < 2; ++dt)
                oacc[t][dt] = MFMA_BF16_K16(pf, vf[dt], oacc[t][dt]);
        }

        if (more) {
            const uint16_t* vp = (const uint16_t*)&vreg;
#pragma unroll
            for (int j = 0; j < 8; ++j) Vt[1 - p][vt_w[j]] = vp[j];
            kf = kf2;
            __syncthreads();  // the only per-tile barrier
            p ^= 1;
        }
    }

    // per-wave l per q (sum over this wave's 16 keys = over quads)
#pragma unroll
    for (int t = 0; t < 4; ++t) {
        float l = lp[t];
        l += __shfl_xor(l, 16);
        l += __shfl_xor(l, 32);
        if (quad == 0) lsh[wv][t * 16 + lo] = l;
    }

    // cross-wave O reduction (fp32, 4 serialized rounds)
    for (int w = 0; w < 4; ++w) {
        if (wv == w) {
#pragma unroll
            for (int t = 0; t < 4; ++t)
#pragma unroll
                for (int dt = 0; dt < 2; ++dt)
#pragma unroll
                    for (int r = 0; r < 4; ++r) {
                        int q = t * 16 + quad * 4 + r;
                        int d = dt * 16 + lo;
                        if (w == 0) Ored[q][d]  = oacc[t][dt][r];
                        else        Ored[q][d] += oacc[t][dt][r];
                    }
        }
        __syncthreads();
    }

    // write unnormalized Op (bf16) + l
    {
        int row = tid >> 2;
        int dc  = (tid & 3) * 8;
        bfrag8 o8;
#pragma unroll
        for (int j = 0; j < 8; ++j) o8[j] = (short)f2b(Ored[row][dc + j]);
        uint16_t* Od = Op + (size_t)sp * SEQ * DHALF;
        *(bfrag8*)&Od[(size_t)(q0 + row) * DHALF + h * DH + dc] = o8;
        if (tid < 64)
            lbuf[((size_t)sp * NH + h) * SEQ + q0 + tid] =
                lsh[0][tid] + lsh[1][tid] + lsh[2][tid] + lsh[3][tid];
    }
}

// O = (Op0 + Op1) / (l0 + l1); 1 thread = 8 cols (within one head).
__global__ __launch_bounds__(256) void combine_kernel(
    const uint16_t* __restrict__ Op, const float* __restrict__ lbuf,
    uint16_t* __restrict__ O)
{
    int t   = blockIdx.x * 256 + threadIdx.x;
    int row = t >> 6;
    int cb  = (t & 63) << 3;
    int h   = cb >> 5;
    float inv = 1.0f / (lbuf[(size_t)h * SEQ + row] +
                        lbuf[((size_t)NH + h) * SEQ + row]);
    const uint16_t* p0 = &Op[(size_t)row * DHALF + cb];
    const uint16_t* p1 = p0 + (size_t)SEQ * DHALF;
    bfrag8 a = *(const bfrag8*)p0;
    bfrag8 b = *(const bfrag8*)p1;
    bfrag8 o;
#pragma unroll
    for (int j = 0; j < 8; ++j)
        o[j] = (short)f2b((b2f((uint16_t)a[j]) + b2f((uint16_t)b[j])) * inv);
    *(bfrag8*)&O[(size_t)row * DHALF + cb] = o;
}

extern "C" void kernel_launch(void* const* d_in, const int* in_sizes, int n_in,
                              void* d_out, int out_size, void* d_ws, size_t ws_size,
                              hipStream_t stream)
{
    const float* x  = (const float*)d_in[0];
    const float* Wq = (const float*)d_in[1];
    const float* Wk = (const float*)d_in[2];
    const float* Wv = (const float*)d_in[3];
    const float* Wo = (const float*)d_in[4];
    const float* bo = (const float*)d_in[5];

    uint16_t* xbf = (uint16_t*)d_ws;
    uint16_t* Wqb = xbf + (size_t)SEQ * DHALF;
    uint16_t* Wkb = Wqb + (size_t)DHALF * DHALF;
    uint16_t* Wvb = Wkb + (size_t)DHALF * DHALF;
    uint16_t* Wob = Wvb + (size_t)DHALF * DHALF;
    uint16_t* Q   = Wob + (size_t)DMODEL * DHALF;
    uint16_t* K   = Q + (size_t)SEQ * DHALF;
    uint16_t* V   = K + (size_t)SEQ * DHALF;
    uint16_t* O   = V + (size_t)SEQ * DHALF;
    uint16_t* Op  = O + (size_t)SEQ * DHALF;
    float*  lbuf  = (float*)(Op + (size_t)NSPLIT * SEQ * DHALF);

    convert_all<<<1664, 256, 0, stream>>>(x, Wq, Wk, Wv, Wo, xbf, Wqb, Wkb, Wvb, Wob);
    qkv_kernel<<<dim3(DHALF / 128, SEQ / 128, 3), 256, 0, stream>>>(
        xbf, Wqb, Wkb, Wvb, Q, K, V);
    attn_kernel<<<dim3(SEQ / 64, NH, NSPLIT), 256, 0, stream>>>(Q, K, V, Op, lbuf);
    combine_kernel<<<1024, 256, 0, stream>>>(Op, lbuf, O);
    outproj_kernel<<<dim3(DMODEL / 128, SEQ / 128), 256, 0, stream>>>(
        O, Wob, bo, (float*)d_out);
}

// Round 11
// 194.515 us; speedup vs baseline: 1.0980x; 1.0980x over previous
//
#include <hip/hip_runtime.h>
#include <stdint.h>

// MultiHeadSelfAttention: E=1024, H=16, S=4096, half=512, Dh=32, scale=sqrt(64)=8
// Inputs fp32. Weights -> bf16 once; x converted inline in qkv. Double-buffered
// 128-tile MFMA GEMMs. Split-K flash attention (R8 structure: waves own 16 q,
// single-buffer staging) + ones-column l-accumulation in MFMA. ws_size-guarded
// NSPLIT (4 if scratch allows, else 2). Exact additive sp-merge in combine.

#define SEQ    4096
#define DMODEL 1024
#define DHALF  512
#define NH     16
#define DH     32

typedef __attribute__((ext_vector_type(4))) float facc4;
typedef __attribute__((ext_vector_type(8))) short bfrag8;

#define MFMA_BF16(a, b, c) __builtin_amdgcn_mfma_f32_16x16x32_bf16((a), (b), (c), 0, 0, 0)

static __device__ __forceinline__ uint16_t f2b(float x) {
    uint32_t u = __float_as_uint(x);
    return (uint16_t)((u + 0x7FFFu + ((u >> 16) & 1u)) >> 16);  // RNE
}
static __device__ __forceinline__ float b2f(uint16_t b) {
    return __uint_as_float(((uint32_t)b) << 16);
}

// 8x fp32 -> 8x bf16 (round-half-away; ties measure-small) via 2add+1perm pairs
static __device__ __forceinline__ bfrag8 cvt8perm(float4 a, float4 b) {
    uint32_t u0 = __float_as_uint(a.x) + 0x8000u, u1 = __float_as_uint(a.y) + 0x8000u;
    uint32_t u2 = __float_as_uint(a.z) + 0x8000u, u3 = __float_as_uint(a.w) + 0x8000u;
    uint32_t u4 = __float_as_uint(b.x) + 0x8000u, u5 = __float_as_uint(b.y) + 0x8000u;
    uint32_t u6 = __float_as_uint(b.z) + 0x8000u, u7 = __float_as_uint(b.w) + 0x8000u;
    union { uint32_t w[4]; bfrag8 r; } u;
    u.w[0] = __builtin_amdgcn_perm(u1, u0, 0x07060302u);
    u.w[1] = __builtin_amdgcn_perm(u3, u2, 0x07060302u);
    u.w[2] = __builtin_amdgcn_perm(u5, u4, 0x07060302u);
    u.w[3] = __builtin_amdgcn_perm(u7, u6, 0x07060302u);
    return u.r;
}

// Weights fp32->bf16: blocks [0,128) Wq, [128,256) Wk, [256,384) Wv, [384,640) Wo.
__global__ __launch_bounds__(256) void convert_w(
    const float* __restrict__ Wq, const float* __restrict__ Wk,
    const float* __restrict__ Wv, const float* __restrict__ Wo,
    uint16_t* __restrict__ q, uint16_t* __restrict__ k,
    uint16_t* __restrict__ v, uint16_t* __restrict__ o)
{
    int zz = blockIdx.x;
    const float* src; uint16_t* dst; size_t off;
    if      (zz < 128) { src = Wq; dst = q; off = (size_t)zz * 2048; }
    else if (zz < 256) { src = Wk; dst = k; off = (size_t)(zz - 128) * 2048; }
    else if (zz < 384) { src = Wv; dst = v; off = (size_t)(zz - 256) * 2048; }
    else               { src = Wo; dst = o; off = (size_t)(zz - 384) * 2048; }
    size_t i = off + (size_t)threadIdx.x * 8;
    float4 a = *(const float4*)&src[i];
    float4 b = *(const float4*)&src[i + 4];
    *(bfrag8*)&dst[i] = cvt8perm(a, b);
}

// ---------------------------------------------------------------------------
// 128x128-tile bf16 GEMM, double-buffered LDS (R9-verified), templated on
// whether A is fp32 (converted inline at stage time) or bf16.
// ---------------------------------------------------------------------------
template <int AF32>
__device__ __forceinline__ void gemm128T(
    const void* __restrict__ A, int lda,
    const uint16_t* __restrict__ B, int ldb,
    void* __restrict__ C, int ldc, int cF32,
    const float* __restrict__ bias, float scale,
    int Kd, int m0, int n0)
{
    __shared__ __align__(16) uint16_t As[2][128 * 40];
    __shared__ __align__(16) uint16_t Bs[2][128 * 40];

    const int tid  = threadIdx.x;
    const int lane = tid & 63;
    const int wv   = tid >> 6;
    const int lo   = lane & 15;
    const int quad = lane >> 4;
    const int srow = tid >> 2;
    const int skq  = (tid & 3) * 8;
    const int rb   = (wv >> 1) * 64;
    const int cb   = (wv & 1) * 64;

    const facc4 ZACC = {0.f, 0.f, 0.f, 0.f};
    facc4 acc[4][4];
#pragma unroll
    for (int i = 0; i < 4; ++i)
#pragma unroll
        for (int j = 0; j < 4; ++j) acc[i][j] = ZACC;

    const float*    fA0 = AF32 ? &((const float*)A)[(size_t)(m0 + srow) * lda + skq] : nullptr;
    const float*    fA1 = AF32 ? &((const float*)A)[(size_t)(m0 + srow + 64) * lda + skq] : nullptr;
    const uint16_t* hA0 = AF32 ? nullptr : &((const uint16_t*)A)[(size_t)(m0 + srow) * lda + skq];
    const uint16_t* hA1 = AF32 ? nullptr : &((const uint16_t*)A)[(size_t)(m0 + srow + 64) * lda + skq];
    const uint16_t* pB0 = &B[(size_t)(n0 + srow) * ldb + skq];
    const uint16_t* pB1 = &B[(size_t)(n0 + srow + 64) * ldb + skq];

    bfrag8 ra0, ra1;
    float4 f0a, f0b, f1a, f1b;
    if (AF32) {
        f0a = *(const float4*)fA0; f0b = *(const float4*)(fA0 + 4);
        f1a = *(const float4*)fA1; f1b = *(const float4*)(fA1 + 4);
    } else {
        ra0 = *(const bfrag8*)hA0;
        ra1 = *(const bfrag8*)hA1;
    }
    bfrag8 rb0 = *(const bfrag8*)pB0;
    bfrag8 rb1 = *(const bfrag8*)pB1;

    if (AF32) {
        *(bfrag8*)&As[0][srow * 40 + skq]        = cvt8perm(f0a, f0b);
        *(bfrag8*)&As[0][(srow + 64) * 40 + skq] = cvt8perm(f1a, f1b);
    } else {
        *(bfrag8*)&As[0][srow * 40 + skq]        = ra0;
        *(bfrag8*)&As[0][(srow + 64) * 40 + skq] = ra1;
    }
    *(bfrag8*)&Bs[0][srow * 40 + skq]        = rb0;
    *(bfrag8*)&Bs[0][(srow + 64) * 40 + skq] = rb1;
    __syncthreads();

    int p = 0;
    for (int kt = 0; kt < Kd; kt += 32) {
        const bool more = (kt + 32 < Kd);
        if (more) {  // fire-and-forget prefetch of next K-slab
            if (AF32) {
                f0a = *(const float4*)(fA0 + kt + 32); f0b = *(const float4*)(fA0 + kt + 36);
                f1a = *(const float4*)(fA1 + kt + 32); f1b = *(const float4*)(fA1 + kt + 36);
            } else {
                ra0 = *(const bfrag8*)(hA0 + kt + 32);
                ra1 = *(const bfrag8*)(hA1 + kt + 32);
            }
            rb0 = *(const bfrag8*)(pB0 + kt + 32);
            rb1 = *(const bfrag8*)(pB1 + kt + 32);
        }

        bfrag8 af[4], bf[4];
#pragma unroll
        for (int i = 0; i < 4; ++i) {
            af[i] = *(const bfrag8*)&As[p][(rb + i * 16 + lo) * 40 + quad * 8];
            bf[i] = *(const bfrag8*)&Bs[p][(cb + i * 16 + lo) * 40 + quad * 8];
        }
#pragma unroll
        for (int i = 0; i < 4; ++i)
#pragma unroll
            for (int j = 0; j < 4; ++j)
                acc[i][j] = MFMA_BF16(af[i], bf[j], acc[i][j]);

        if (more) {
            if (AF32) {
                *(bfrag8*)&As[1 - p][srow * 40 + skq]        = cvt8perm(f0a, f0b);
                *(bfrag8*)&As[1 - p][(srow + 64) * 40 + skq] = cvt8perm(f1a, f1b);
            } else {
                *(bfrag8*)&As[1 - p][srow * 40 + skq]        = ra0;
                *(bfrag8*)&As[1 - p][(srow + 64) * 40 + skq] = ra1;
            }
            *(bfrag8*)&Bs[1 - p][srow * 40 + skq]        = rb0;
            *(bfrag8*)&Bs[1 - p][(srow + 64) * 40 + skq] = rb1;
            __syncthreads();  // the only barrier per iter
            p ^= 1;
        }
    }

#pragma unroll
    for (int j = 0; j < 4; ++j) {
        int col  = n0 + cb + j * 16 + lo;
        float bv = bias ? bias[col] : 0.f;
#pragma unroll
        for (int i = 0; i < 4; ++i) {
#pragma unroll
            for (int r = 0; r < 4; ++r) {
                int row = m0 + rb + i * 16 + quad * 4 + r;
                float v = acc[i][j][r] * scale + bv;
                if (cF32) ((float*)C)[(size_t)row * ldc + col] = v;
                else      ((uint16_t*)C)[(size_t)row * ldc + col] = f2b(v);
            }
        }
    }
}

#define SC_Q (0.125f * 1.4426950408889634f)  // softmax scale * log2(e), folded into Q

// QKV from fp32 x directly (left half via lda=DMODEL, cols < 512 only).
__global__ __launch_bounds__(256, 2) void qkv_kernel(
    const float* __restrict__ x,
    const uint16_t* __restrict__ Wqb, const uint16_t* __restrict__ Wkb,
    const uint16_t* __restrict__ Wvb,
    uint16_t* __restrict__ Q, uint16_t* __restrict__ K, uint16_t* __restrict__ V)
{
    const int z = blockIdx.z;
    const uint16_t* W = (z == 0) ? Wqb : (z == 1) ? Wkb : Wvb;
    uint16_t* Out     = (z == 0) ? Q   : (z == 1) ? K   : V;
    float scale       = (z == 0) ? SC_Q : 1.0f;
    gemm128T<1>(x, DMODEL, W, DHALF, Out, DHALF, 0, nullptr, scale, DHALF,
                blockIdx.y * 128, blockIdx.x * 128);
}

__global__ __launch_bounds__(256, 2) void outproj_kernel(
    const uint16_t* __restrict__ O, const uint16_t* __restrict__ Wob,
    const float* __restrict__ bo, float* __restrict__ Y)
{
    gemm128T<0>(O, DHALF, Wob, DHALF, Y, DMODEL, 1, bo, 1.0f, DHALF,
                blockIdx.y * 128, blockIdx.x * 128);
}

// ---------------------------------------------------------------------------
// Split-K flash attention (R8 structure, best measured): waves own 16 q-rows,
// single-buffered K/V staging + register prefetch, fixed-max softmax.
// NEW: l accumulated by an extra MFMA against an all-ones b-fragment ->
// every lane holds l for its own q-rows (kills lpart adds + all shuffles,
// and l is consistent with the bf16 P used in PV).
// ---------------------------------------------------------------------------
__global__ __launch_bounds__(256) void attn_kernel(
    const uint16_t* __restrict__ Q, const uint16_t* __restrict__ Kb,
    const uint16_t* __restrict__ Vb, uint16_t* __restrict__ Op,
    float* __restrict__ lbuf, int kspan)
{
    __shared__ __align__(16) uint16_t Ks[64 * 40];     // K tile [key][d]
    __shared__ __align__(16) uint16_t Vt[32 * 64];     // V^T [d][key], swizzled
    __shared__ __align__(16) uint16_t Ps[4 * 16 * 72]; // per-wave P [q][key]

    const int tid  = threadIdx.x;
    const int lane = tid & 63;
    const int wv   = tid >> 6;
    const int lo   = lane & 15;
    const int quad = lane >> 4;
    const int h    = blockIdx.y;
    const int q0   = blockIdx.x * 64;
    const int sp   = blockIdx.z;
    const int srow = tid >> 2;
    const int skq  = (tid & 3) * 8;

    const facc4 ZACC = {0.f, 0.f, 0.f, 0.f};

    const bfrag8 qf = *(const bfrag8*)&Q[(size_t)(q0 + wv * 16 + lo) * DHALF + h * DH + quad * 8];

    bfrag8 ones;
#pragma unroll
    for (int j = 0; j < 8; ++j) ones[j] = (short)0x3F80;  // bf16 1.0

    int vt_w[8];
#pragma unroll
    for (int j = 0; j < 8; ++j) {
        int d  = skq + j;
        int Rd = ((d & 7) + 2 * (d >> 3)) & 7;
        vt_w[j] = d * 64 + ((((srow >> 3) + Rd) & 7) << 3) + (srow & 7);
    }
    int vt_r[2][2];
#pragma unroll
    for (int dt = 0; dt < 2; ++dt) {
        int d  = dt * 16 + lo;
        int Rd = ((d & 7) + 2 * (d >> 3)) & 7;
#pragma unroll
        for (int c = 0; c < 2; ++c)
            vt_r[c][dt] = d * 64 + ((((c * 4 + quad) + Rd) & 7) << 3);
    }
    const int pbase = wv * (16 * 72);
    const int ps_w  = pbase + lo * 72 + 4 * quad;
    const int ps_r  = pbase + lo * 72 + quad * 8;
    const int ks_r  = lo * 40 + quad * 8;

    const uint16_t* pK = &Kb[(size_t)srow * DHALF + h * DH + skq];
    const uint16_t* pV = &Vb[(size_t)srow * DHALF + h * DH + skq];

    facc4 oacc[2], oaccL;
    oacc[0] = ZACC; oacc[1] = ZACC; oaccL = ZACC;

    const int kb0  = sp * kspan;
    const int kend = kb0 + kspan;

    float4 kreg = *(const float4*)(pK + (size_t)kb0 * DHALF);
    float4 vreg = *(const float4*)(pV + (size_t)kb0 * DHALF);

    for (int kb = kb0; kb < kend; kb += 64) {
        *(float4*)&Ks[srow * 40 + skq] = kreg;
        {
            const uint16_t* vp = (const uint16_t*)&vreg;
#pragma unroll
            for (int j = 0; j < 8; ++j) Vt[vt_w[j]] = vp[j];
        }
        __syncthreads();

        if (kb + 64 < kend) {  // fire-and-forget prefetch of next K/V tile
            kreg = *(const float4*)(pK + (size_t)(kb + 64) * DHALF);
            vreg = *(const float4*)(pV + (size_t)(kb + 64) * DHALF);
        }

#pragma unroll
        for (int t = 0; t < 4; ++t) {
            bfrag8 kf = *(const bfrag8*)&Ks[t * 640 + ks_r];
            facc4 s = MFMA_BF16(kf, qf, ZACC);  // D[key=16t+4q+r][q=lo], pre-scaled
            float p0 = __builtin_amdgcn_exp2f(s[0]);
            float p1 = __builtin_amdgcn_exp2f(s[1]);
            float p2 = __builtin_amdgcn_exp2f(s[2]);
            float p3 = __builtin_amdgcn_exp2f(s[3]);
            uint32_t u0 = __float_as_uint(p0) + 0x8000u;
            uint32_t u1 = __float_as_uint(p1) + 0x8000u;
            uint32_t u2 = __float_as_uint(p2) + 0x8000u;
            uint32_t u3 = __float_as_uint(p3) + 0x8000u;
            uint2 w;
            w.x = __builtin_amdgcn_perm(u1, u0, 0x07060302u);
            w.y = __builtin_amdgcn_perm(u3, u2, 0x07060302u);
            *(uint2*)&Ps[ps_w + 16 * t] = w;  // single ds_write_b64
        }
        __builtin_amdgcn_wave_barrier();  // Ps is same-wave-only; pin DS order

#pragma unroll
        for (int c = 0; c < 2; ++c) {
            bfrag8 pf = *(const bfrag8*)&Ps[ps_r + c * 32];
#pragma unroll
            for (int dt = 0; dt < 2; ++dt) {
                bfrag8 vf = *(const bfrag8*)&Vt[vt_r[c][dt]];
                oacc[dt] = MFMA_BF16(pf, vf, oacc[dt]);
            }
            oaccL = MFMA_BF16(pf, ones, oaccL);  // l rows: D[q][*] = sum_k P[q][k]
        }
        __syncthreads();  // protect Ks/Vt restage
    }

    // l for q-row quad*4+r sits in oaccL[r] (same on all lo lanes)
    if (lo == 0) {
#pragma unroll
        for (int r = 0; r < 4; ++r)
            lbuf[((size_t)sp * NH + h) * SEQ + q0 + wv * 16 + quad * 4 + r] = oaccL[r];
    }

    uint16_t* Od = Op + (size_t)sp * SEQ * DHALF;
#pragma unroll
    for (int r = 0; r < 4; ++r) {
        int row = q0 + wv * 16 + quad * 4 + r;
        Od[(size_t)row * DHALF + h * DH + lo]      = f2b(oacc[0][r]);  // unnormalized
        Od[(size_t)row * DHALF + h * DH + 16 + lo] = f2b(oacc[1][r]);
    }
}

// O = sum_sp(Op_sp) / sum_sp(l_sp); 1 thread = 8 cols (within one head).
__global__ __launch_bounds__(256) void combine_kernel(
    const uint16_t* __restrict__ Op, const float* __restrict__ lbuf,
    uint16_t* __restrict__ O, int ns)
{
    int t   = blockIdx.x * 256 + threadIdx.x;
    int row = t >> 6;
    int cb  = (t & 63) << 3;
    int h   = cb >> 5;
    float l = 0.f;
    float acc[8] = {0.f, 0.f, 0.f, 0.f, 0.f, 0.f, 0.f, 0.f};
    for (int sp = 0; sp < ns; ++sp) {
        l += lbuf[((size_t)sp * NH + h) * SEQ + row];
        bfrag8 a = *(const bfrag8*)&Op[(size_t)sp * SEQ * DHALF + (size_t)row * DHALF + cb];
#pragma unroll
        for (int j = 0; j < 8; ++j) acc[j] += b2f((uint16_t)a[j]);
    }
    float inv = 1.0f / l;
    bfrag8 o;
#pragma unroll
    for (int j = 0; j < 8; ++j) o[j] = (short)f2b(acc[j] * inv);
    *(bfrag8*)&O[(size_t)row * DHALF + cb] = o;
}

extern "C" void kernel_launch(void* const* d_in, const int* in_sizes, int n_in,
                              void* d_out, int out_size, void* d_ws, size_t ws_size,
                              hipStream_t stream)
{
    const float* x  = (const float*)d_in[0];
    const float* Wq = (const float*)d_in[1];
    const float* Wk = (const float*)d_in[2];
    const float* Wv = (const float*)d_in[3];
    const float* Wo = (const float*)d_in[4];
    const float* bo = (const float*)d_in[5];

    // ws (u16 elems): Wqb/Wkb/Wvb 256K ea | Wob 512K | Q,K,V,O 2M ea | Op ns*2M
    // then lbuf (ns*NH*SEQ fp32). ns=4 needs ~37.3 MB; fall back to 2 if short.
    size_t fixed_e = 3 * (size_t)DHALF * DHALF + (size_t)DMODEL * DHALF
                   + 4 * (size_t)SEQ * DHALF;
    size_t need4 = (fixed_e + 4 * (size_t)SEQ * DHALF) * 2
                 + 4 * (size_t)NH * SEQ * 4;
    const int ns = (ws_size >= need4) ? 4 : 2;

    uint16_t* Wqb = (uint16_t*)d_ws;
    uint16_t* Wkb = Wqb + (size_t)DHALF * DHALF;
    uint16_t* Wvb = Wkb + (size_t)DHALF * DHALF;
    uint16_t* Wob = Wvb + (size_t)DHALF * DHALF;
    uint16_t* Q   = Wob + (size_t)DMODEL * DHALF;
    uint16_t* K   = Q + (size_t)SEQ * DHALF;
    uint16_t* V   = K + (size_t)SEQ * DHALF;
    uint16_t* O   = V + (size_t)SEQ * DHALF;
    uint16_t* Op  = O + (size_t)SEQ * DHALF;
    float*  lbuf  = (float*)(Op + (size_t)ns * SEQ * DHALF);

    convert_w<<<640, 256, 0, stream>>>(Wq, Wk, Wv, Wo, Wqb, Wkb, Wvb, Wob);
    qkv_kernel<<<dim3(DHALF / 128, SEQ / 128, 3), 256, 0, stream>>>(
        x, Wqb, Wkb, Wvb, Q, K, V);
    attn_kernel<<<dim3(SEQ / 64, NH, ns), 256, 0, stream>>>(Q, K, V, Op, lbuf, SEQ / ns);
    combine_kernel<<<1024, 256, 0, stream>>>(Op, lbuf, O, ns);
    outproj_kernel<<<dim3(DMODEL / 128, SEQ / 128), 256, 0, stream>>>(
        O, Wob, bo, (float*)d_out);
}